// Round 13
// baseline (32.279 us; speedup 1.0000x reference)
//
#include <hip/hip_runtime.h>
#include <hip/hip_bf16.h>

#define NNZ   104858
#define NB    1024
#define NIN   1024
#define NOUT  1024

typedef __bf16 bf16;
typedef bf16  bf16x8 __attribute__((ext_vector_type(8)));
typedef float f32x4  __attribute__((ext_vector_type(4)));

// ---------------- pre: zero Wd | convert x->bf16 ----------------
__global__ __launch_bounds__(256)
void k_pre(const float* __restrict__ x, float* __restrict__ Wd,
           bf16* __restrict__ xb) {
    const int b = blockIdx.x, t = threadIdx.x;
    if (b < 512) {
        float4 z = {0.f, 0.f, 0.f, 0.f};
        float4* w4 = (float4*)Wd;
        int i = (b * 256 + t) * 2;
        w4[i] = z; w4[i + 1] = z;
    } else {
        const int base = ((b - 512) * 256 + t) * 8;
        const float4* s4 = (const float4*)(x + base);
        float4 v0 = s4[0], v1 = s4[1];
        bf16x8 o;
        o[0] = (bf16)v0.x; o[1] = (bf16)v0.y; o[2] = (bf16)v0.z; o[3] = (bf16)v0.w;
        o[4] = (bf16)v1.x; o[5] = (bf16)v1.y; o[6] = (bf16)v1.z; o[7] = (bf16)v1.w;
        *(bf16x8*)(xb + base) = o;
    }
}

// ---------------- densify: Wd[r][c] += w_k (f32 atomics; duplicates sum) ----
__global__ __launch_bounds__(256)
void k_densify(const int* __restrict__ idx, const float* __restrict__ w,
               float* __restrict__ Wd) {
    int k = blockIdx.x * 256 + threadIdx.x;
    if (k < NNZ) {
        int r = idx[k] & (NOUT - 1);
        int c = idx[NNZ + k] & (NIN - 1);
        atomicAdd(&Wd[r * NIN + c], w[k]);
    }
}

// ---------------- GEMM: out = x_bf16 * bf16(Wd)^T + bias ----------------
// R7 core with BK=128 (4 K-steps instead of 8): same 64x64 tile, 512 threads,
// in-block split-K=2, A via global_load_lds (lane-linear dest f=i*256+th,
// pre-swizzled source g^(row&15)), B reg-staged f32->bf16 with matching
// write-side XOR swizzle, B(ks+1) prefetch under MFMA. Halves the number of
// exposed barrier drains at identical occupancy (1 block/CU; 80 KB LDS).
// K-summation order identical to R7 -> absmax bit-identical.
__device__ __forceinline__ void gload_lds16(const void* g, void* l) {
    __builtin_amdgcn_global_load_lds((const __attribute__((address_space(1))) void*)g,
                                     (__attribute__((address_space(3))) void*)l,
                                     16, 0, 0);
}

__global__ __launch_bounds__(512)
void k_gemm(const bf16* __restrict__ A, const float* __restrict__ Wd,
            const float* __restrict__ bias, float* __restrict__ out) {
    __shared__ __align__(16) bf16 As[2][64 * 128];   // [half] 16 KB each
    __shared__ __align__(16) bf16 Bs[2][64 * 128];
    __shared__ f32x4 red[4][64][4];                  // 16 KB

    const int b  = blockIdx.x;
    const int id = (b & 7) * 32 + (b >> 3);          // XCD-aware swizzle
    const int m0 = (id & 15) * 64, n0 = (id >> 4) * 64;

    const int t    = threadIdx.x;
    const int lane = t & 63;
    const int wv   = t >> 6;            // 0..7
    const int half = wv >> 2;           // K split
    const int w4   = wv & 3, wr = w4 >> 1, wc = w4 & 1;
    const int fr   = lane & 15, fg = lane >> 4;

    const int th   = t & 255;           // staging thread id within half
    const int arow = th >> 4;           // A: row within 16-row group (+i*16)
    const int ag   = th & 15;           // A: 16B granule within 256B row
    const int brow = th >> 2;           // B: 0..63
    const int bq   = th & 3;            // B: granule quad

    f32x4 acc[2][2] = {};

    const float* wrow = Wd + (size_t)(n0 + brow) * NIN + half * 512;

    // preload B(ks=0): 4 granules x 8 floats
    float4 bv[8];
    #pragma unroll
    for (int j = 0; j < 4; ++j) {
        const float4* p = (const float4*)(wrow + (bq * 4 + j) * 8);
        bv[2 * j] = p[0]; bv[2 * j + 1] = p[1];
    }

    for (int ks = 0; ks < 4; ++ks) {
        const int kb = half * 512 + ks * 128;
        // stage A: 4 issues, dest lane-linear (f = i*256+th), source pre-swizzled
        #pragma unroll
        for (int i = 0; i < 4; ++i) {
            int row = i * 16 + arow;
            int g2  = ag ^ (row & 15);
            gload_lds16(A + (size_t)(m0 + row) * NIN + kb + g2 * 8,
                        As[half] + row * 128 + ag * 8);
        }
        // write B(ks) from regs: convert f32->bf16, swizzled ds_write
        #pragma unroll
        for (int j = 0; j < 4; ++j) {
            float4 v0 = bv[2 * j], v1 = bv[2 * j + 1];
            bf16x8 o;
            o[0] = (bf16)v0.x; o[1] = (bf16)v0.y; o[2] = (bf16)v0.z; o[3] = (bf16)v0.w;
            o[4] = (bf16)v1.x; o[5] = (bf16)v1.y; o[6] = (bf16)v1.z; o[7] = (bf16)v1.w;
            int g = bq * 4 + j;
            *(bf16x8*)(Bs[half] + brow * 128 + (g ^ (brow & 15)) * 8) = o;
        }
        __syncthreads();

        // prefetch B(ks+1) under MFMA
        if (ks < 3) {
            #pragma unroll
            for (int j = 0; j < 4; ++j) {
                const float4* p = (const float4*)(wrow + (ks + 1) * 128 + (bq * 4 + j) * 8);
                bv[2 * j] = p[0]; bv[2 * j + 1] = p[1];
            }
        }

        bf16x8 af[2][4], bfr[2][4];
        #pragma unroll
        for (int mi = 0; mi < 2; ++mi) {
            int row = wr * 32 + mi * 16 + fr;
            #pragma unroll
            for (int kk = 0; kk < 4; ++kk) {
                int gsw = (kk * 4 + fg) ^ (row & 15);
                af[mi][kk] = *(const bf16x8*)(As[half] + row * 128 + gsw * 8);
            }
        }
        #pragma unroll
        for (int ni = 0; ni < 2; ++ni) {
            int row = wc * 32 + ni * 16 + fr;
            #pragma unroll
            for (int kk = 0; kk < 4; ++kk) {
                int gsw = (kk * 4 + fg) ^ (row & 15);
                bfr[ni][kk] = *(const bf16x8*)(Bs[half] + row * 128 + gsw * 8);
            }
        }
        #pragma unroll
        for (int kk = 0; kk < 4; ++kk)
            #pragma unroll
            for (int mi = 0; mi < 2; ++mi)
                #pragma unroll
                for (int ni = 0; ni < 2; ++ni)
                    acc[mi][ni] = __builtin_amdgcn_mfma_f32_16x16x32_bf16(
                        af[mi][kk], bfr[ni][kk], acc[mi][ni], 0, 0, 0);
        __syncthreads();
    }

    // epilogue: cross-half reduce, single plain-store writer (replay-stable)
    if (half == 1) {
        #pragma unroll
        for (int mi = 0; mi < 2; ++mi)
            #pragma unroll
            for (int ni = 0; ni < 2; ++ni)
                red[w4][lane][mi * 2 + ni] = acc[mi][ni];
    }
    __syncthreads();
    if (half == 0) {
        #pragma unroll
        for (int mi = 0; mi < 2; ++mi) {
            #pragma unroll
            for (int ni = 0; ni < 2; ++ni) {
                f32x4 p = red[w4][lane][mi * 2 + ni];
                int row0 = m0 + wr * 32 + mi * 16 + fg * 4;
                int col  = n0 + wc * 32 + ni * 16 + fr;
                float bb = bias[col];
                #pragma unroll
                for (int j = 0; j < 4; ++j)
                    out[(size_t)(row0 + j) * NOUT + col] = acc[mi][ni][j] + p[j] + bb;
            }
        }
    }
}

// ---------------- launch ----------------
static inline size_t align256(size_t v) { return (v + 255) & ~(size_t)255; }

extern "C" void kernel_launch(void* const* d_in, const int* in_sizes, int n_in,
                              void* d_out, int out_size, void* d_ws, size_t ws_size,
                              hipStream_t stream) {
    const float* x    = (const float*)d_in[0];   // [NB][NIN]
    const float* wts  = (const float*)d_in[1];   // [NNZ]
    const float* bias = (const float*)d_in[2];   // [NOUT]
    const int*   idx  = (const int*)d_in[3];     // [2][NNZ] int32

    char* ws = (char*)d_ws;
    size_t off = 0;
    float* Wd = (float*)(ws + off); off = align256(off + (size_t)NOUT * NIN * 4);  // 4 MB
    bf16*  xb = (bf16*) (ws + off); off = align256(off + (size_t)NB * NIN * 2);    // 2 MB

    const int nb_nnz = (NNZ + 255) / 256;

    k_pre<<<1024, 256, 0, stream>>>(x, Wd, xb);
    k_densify<<<nb_nnz, 256, 0, stream>>>(idx, wts, Wd);
    k_gemm<<<256, 512, 0, stream>>>(xb, Wd, bias, (float*)d_out);
}

// Round 14
// 29.056 us; speedup vs baseline: 1.1109x; 1.1109x over previous
//
#include <hip/hip_runtime.h>
#include <hip/hip_bf16.h>

#define NNZ   104858
#define NB    1024
#define NIN   1024
#define NOUT  1024

typedef __bf16 bf16;
typedef bf16  bf16x8 __attribute__((ext_vector_type(8)));
typedef float f32x4  __attribute__((ext_vector_type(4)));

// ---------------- pre: zero Wd | convert x->bf16 ----------------
__global__ __launch_bounds__(256)
void k_pre(const float* __restrict__ x, float* __restrict__ Wd,
           bf16* __restrict__ xb) {
    const int b = blockIdx.x, t = threadIdx.x;
    if (b < 512) {
        float4 z = {0.f, 0.f, 0.f, 0.f};
        float4* w4 = (float4*)Wd;
        int i = (b * 256 + t) * 2;
        w4[i] = z; w4[i + 1] = z;
    } else {
        const int base = ((b - 512) * 256 + t) * 8;
        const float4* s4 = (const float4*)(x + base);
        float4 v0 = s4[0], v1 = s4[1];
        bf16x8 o;
        o[0] = (bf16)v0.x; o[1] = (bf16)v0.y; o[2] = (bf16)v0.z; o[3] = (bf16)v0.w;
        o[4] = (bf16)v1.x; o[5] = (bf16)v1.y; o[6] = (bf16)v1.z; o[7] = (bf16)v1.w;
        *(bf16x8*)(xb + base) = o;
    }
}

// ---------------- densify: Wd[r][c] += w_k (f32 atomics; duplicates sum) ----
__global__ __launch_bounds__(256)
void k_densify(const int* __restrict__ idx, const float* __restrict__ w,
               float* __restrict__ Wd) {
    int k = blockIdx.x * 256 + threadIdx.x;
    if (k < NNZ) {
        int r = idx[k] & (NOUT - 1);
        int c = idx[NNZ + k] & (NIN - 1);
        atomicAdd(&Wd[r * NIN + c], w[k]);
    }
}

// ---------------- GEMM: out = x_bf16 * bf16(Wd)^T + bias ----------------
// Best-measured configuration (R7, 28.99 us): 64x64 tile, 512 threads
// (8 waves), in-block split-K=2, A via global_load_lds (pre-swizzled source),
// B reg-staged f32->bf16 with write-side XOR swizzle, B-prefetch under MFMA,
// XCD-aware block swizzle, single plain-store writer of d_out (replay-stable).
__device__ __forceinline__ void gload_lds16(const void* g, void* l) {
    __builtin_amdgcn_global_load_lds((const __attribute__((address_space(1))) void*)g,
                                     (__attribute__((address_space(3))) void*)l,
                                     16, 0, 0);
}

__global__ __launch_bounds__(512)
void k_gemm(const bf16* __restrict__ A, const float* __restrict__ Wd,
            const float* __restrict__ bias, float* __restrict__ out) {
    __shared__ __align__(16) bf16 As[2][64 * 64];   // [half]
    __shared__ __align__(16) bf16 Bs[2][64 * 64];
    __shared__ f32x4 red[4][64][4];                 // 16 KB reduce buffer

    const int b  = blockIdx.x;
    const int id = (b & 7) * 32 + (b >> 3);         // XCD-aware swizzle
    const int m0 = (id & 15) * 64, n0 = (id >> 4) * 64;

    const int t    = threadIdx.x;
    const int lane = t & 63;
    const int wv   = t >> 6;            // 0..7
    const int half = wv >> 2;           // K split
    const int w4   = wv & 3, wr = w4 >> 1, wc = w4 & 1;
    const int fr   = lane & 15, fg = lane >> 4;

    const int th   = t & 255;           // staging thread id within half
    const int srow = th >> 3;           // A: 0..31
    const int sg   = th & 7;            // A: 16B granule in 128B row
    const int brow = th >> 2;           // B: 0..63
    const int bq   = th & 3;            // B: 16-f32 quarter of the 64-col slice

    f32x4 acc[2][2] = {};

    const float* wrow = Wd + (size_t)(n0 + brow) * NIN + half * 512;
    float4 bv0, bv1, bv2, bv3;
    {
        const float4* p = (const float4*)(wrow + bq * 16);
        bv0 = p[0]; bv1 = p[1]; bv2 = p[2]; bv3 = p[3];
    }

    for (int ks = 0; ks < 8; ++ks) {
        const int kbase = half * 512 + ks * 64;
        #pragma unroll
        for (int i = 0; i < 2; ++i) {
            int row = i * 32 + srow;
            int g2  = sg ^ (row & 7);
            gload_lds16(A + (size_t)(m0 + row) * NIN + kbase + g2 * 8,
                        As[half] + row * 64 + sg * 8);
        }
        {
            bf16x8 o0, o1;
            o0[0] = (bf16)bv0.x; o0[1] = (bf16)bv0.y; o0[2] = (bf16)bv0.z; o0[3] = (bf16)bv0.w;
            o0[4] = (bf16)bv1.x; o0[5] = (bf16)bv1.y; o0[6] = (bf16)bv1.z; o0[7] = (bf16)bv1.w;
            o1[0] = (bf16)bv2.x; o1[1] = (bf16)bv2.y; o1[2] = (bf16)bv2.z; o1[3] = (bf16)bv2.w;
            o1[4] = (bf16)bv3.x; o1[5] = (bf16)bv3.y; o1[6] = (bf16)bv3.z; o1[7] = (bf16)bv3.w;
            int g0 = (bq * 2)     ^ (brow & 7);
            int g1 = (bq * 2 + 1) ^ (brow & 7);
            *(bf16x8*)(Bs[half] + brow * 64 + g0 * 8) = o0;
            *(bf16x8*)(Bs[half] + brow * 64 + g1 * 8) = o1;
        }
        __syncthreads();

        if (ks < 7) {
            const float4* p = (const float4*)(wrow + (ks + 1) * 64 + bq * 16);
            bv0 = p[0]; bv1 = p[1]; bv2 = p[2]; bv3 = p[3];
        }

        bf16x8 af[2][2], bfr[2][2];
        #pragma unroll
        for (int mi = 0; mi < 2; ++mi) {
            int row = wr * 32 + mi * 16 + fr;
            #pragma unroll
            for (int kk = 0; kk < 2; ++kk) {
                int gsw = (kk * 4 + fg) ^ (row & 7);
                af[mi][kk] = *(const bf16x8*)(As[half] + row * 64 + gsw * 8);
            }
        }
        #pragma unroll
        for (int ni = 0; ni < 2; ++ni) {
            int row = wc * 32 + ni * 16 + fr;
            #pragma unroll
            for (int kk = 0; kk < 2; ++kk) {
                int gsw = (kk * 4 + fg) ^ (row & 7);
                bfr[ni][kk] = *(const bf16x8*)(Bs[half] + row * 64 + gsw * 8);
            }
        }
        #pragma unroll
        for (int mi = 0; mi < 2; ++mi)
            #pragma unroll
            for (int ni = 0; ni < 2; ++ni)
                #pragma unroll
                for (int kk = 0; kk < 2; ++kk)
                    acc[mi][ni] = __builtin_amdgcn_mfma_f32_16x16x32_bf16(
                        af[mi][kk], bfr[ni][kk], acc[mi][ni], 0, 0, 0);
        __syncthreads();
    }

    if (half == 1) {
        #pragma unroll
        for (int mi = 0; mi < 2; ++mi)
            #pragma unroll
            for (int ni = 0; ni < 2; ++ni)
                red[w4][lane][mi * 2 + ni] = acc[mi][ni];
    }
    __syncthreads();
    if (half == 0) {
        #pragma unroll
        for (int mi = 0; mi < 2; ++mi) {
            #pragma unroll
            for (int ni = 0; ni < 2; ++ni) {
                f32x4 p = red[w4][lane][mi * 2 + ni];
                int row0 = m0 + wr * 32 + mi * 16 + fg * 4;
                int col  = n0 + wc * 32 + ni * 16 + fr;
                float bb = bias[col];
                #pragma unroll
                for (int j = 0; j < 4; ++j)
                    out[(size_t)(row0 + j) * NOUT + col] = acc[mi][ni][j] + p[j] + bb;
            }
        }
    }
}

// ---------------- launch ----------------
static inline size_t align256(size_t v) { return (v + 255) & ~(size_t)255; }

extern "C" void kernel_launch(void* const* d_in, const int* in_sizes, int n_in,
                              void* d_out, int out_size, void* d_ws, size_t ws_size,
                              hipStream_t stream) {
    const float* x    = (const float*)d_in[0];   // [NB][NIN]
    const float* wts  = (const float*)d_in[1];   // [NNZ]
    const float* bias = (const float*)d_in[2];   // [NOUT]
    const int*   idx  = (const int*)d_in[3];     // [2][NNZ] int32

    char* ws = (char*)d_ws;
    size_t off = 0;
    float* Wd = (float*)(ws + off); off = align256(off + (size_t)NOUT * NIN * 4);  // 4 MB
    bf16*  xb = (bf16*) (ws + off); off = align256(off + (size_t)NB * NIN * 2);    // 2 MB

    const int nb_nnz = (NNZ + 255) / 256;

    k_pre<<<1024, 256, 0, stream>>>(x, Wd, xb);
    k_densify<<<nb_nnz, 256, 0, stream>>>(idx, wts, Wd);
    k_gemm<<<256, 512, 0, stream>>>(xb, Wd, bias, (float*)d_out);
}